// Round 1
// baseline (10.242 us; speedup 1.0000x reference)
//
#include <hip/hip_runtime.h>

// InsulationScore: out[b,i] = mean of x[b, i:i+10, i+11:i+21]  (10x10 window
// on the diagonal band), x: [4,1,4096,4096] f32, out: [4,1,4076] f32.

#define W      10
#define NN     4096
#define NOUT   (NN - 2 * W)          // 4076
#define BPC    4                      // B*C
#define OUTS_PER_BLOCK 256
#define BAND_W 19                     // offsets c - r in [2, 20]
#define ROW_PAD 21                    // gcd(21,32)=1 -> conflict-free LDS

__global__ __launch_bounds__(OUTS_PER_BLOCK)
void insulation_kernel(const float* __restrict__ x, float* __restrict__ out) {
    const int b  = blockIdx.y;                       // batch*channel index
    const int i0 = blockIdx.x * OUTS_PER_BLOCK;      // first output of chunk
    const int nout_blk = min(OUTS_PER_BLOCK, NOUT - i0);
    const int nrows    = nout_blk + W - 1;           // rows i0 .. i0+nout_blk+8

    __shared__ float band[(OUTS_PER_BLOCK + W - 1) * ROW_PAD];

    const float* xb = x + (size_t)b * NN * NN;

    // Stage the diagonal band: band[lr][o] = x[i0+lr][ (i0+lr) + 2 + o ]
    const int total = nrows * BAND_W;
    for (int idx = threadIdx.x; idx < total; idx += blockDim.x) {
        const int lr = idx / BAND_W;
        const int o  = idx - lr * BAND_W;
        const int r  = i0 + lr;
        const int c  = r + 2 + o;
        float v = 0.0f;
        if (c < NN) v = xb[(size_t)r * NN + c];
        band[lr * ROW_PAD + o] = v;
    }
    __syncthreads();

    const int li = threadIdx.x;
    if (li < nout_blk) {
        // out(i) = sum_{rr=0..9} sum_{cc=0..9} x[i+rr][i+11+cc]
        // band offset o = (i+11+cc) - (i+rr) - 2 = (W-1) - rr + cc
        float acc = 0.0f;
        #pragma unroll
        for (int rr = 0; rr < W; ++rr) {
            const float* p = &band[(li + rr) * ROW_PAD + (W - 1 - rr)];
            #pragma unroll
            for (int cc = 0; cc < W; ++cc) acc += p[cc];
        }
        out[(size_t)b * NOUT + (i0 + li)] = acc * (1.0f / (W * W));
    }
}

extern "C" void kernel_launch(void* const* d_in, const int* in_sizes, int n_in,
                              void* d_out, int out_size, void* d_ws, size_t ws_size,
                              hipStream_t stream) {
    const float* x = (const float*)d_in[0];
    float* out = (float*)d_out;
    dim3 grid((NOUT + OUTS_PER_BLOCK - 1) / OUTS_PER_BLOCK, BPC);
    dim3 block(OUTS_PER_BLOCK);
    insulation_kernel<<<grid, block, 0, stream>>>(x, out);
}

// Round 2
// 9.772 us; speedup vs baseline: 1.0481x; 1.0481x over previous
//
#include <hip/hip_runtime.h>

// InsulationScore: out[b,i] = mean of x[b, i:i+10, i+11:i+21]  (10x10 window
// on the diagonal band), x: [4,1,4096,4096] f32, out: [4,1,4076] f32.
//
// R2: staging fully unrolled + register-staged so all 20 global loads are in
// flight simultaneously (R1's loop serialized load->ds_write 20x at cold-HBM
// latency ~900cyc each ≈ 7.5us).

#define W      10
#define NN     4096
#define NOUT   (NN - 2 * W)          // 4076
#define BPC    4                      // B*C
#define OUTS_PER_BLOCK 256
#define BAND_W 19                     // offsets c - r in [2, 20]
#define ROW_PAD 21                    // stride 21 vs 32 banks -> 2 lanes/bank (free)
#define NROWS  (OUTS_PER_BLOCK + W - 1)   // 265
#define TOT    (NROWS * BAND_W)           // 5035
#define ITERS  ((TOT + OUTS_PER_BLOCK - 1) / OUTS_PER_BLOCK)  // 20

__global__ __launch_bounds__(OUTS_PER_BLOCK)
void insulation_kernel(const float* __restrict__ x, float* __restrict__ out) {
    const int b  = blockIdx.y;                       // batch*channel index
    const int i0 = blockIdx.x * OUTS_PER_BLOCK;      // first output of chunk

    __shared__ float band[NROWS * ROW_PAD];

    const float* xb = x + (size_t)b * NN * NN;

    // Stage the diagonal band: band[lr][o] = x[i0+lr][ (i0+lr) + 2 + o ]
    // All loads issued first (independent), then written to LDS.
    float v[ITERS];
    #pragma unroll
    for (int k = 0; k < ITERS; ++k) {
        const int idx = threadIdx.x + k * OUTS_PER_BLOCK;
        const int lr  = idx / BAND_W;               // const-div -> mulhi
        const int o   = idx - lr * BAND_W;
        int r = i0 + lr;  if (r > NN - 1) r = NN - 1;   // clamp; clamped slots
        int c = r + 2 + o; if (c > NN - 1) c = NN - 1;  // are never read
        v[k] = xb[(size_t)r * NN + c];
    }
    #pragma unroll
    for (int k = 0; k < ITERS; ++k) {
        const int idx = threadIdx.x + k * OUTS_PER_BLOCK;
        const int lr  = idx / BAND_W;
        const int o   = idx - lr * BAND_W;
        if (idx < TOT) band[lr * ROW_PAD + o] = v[k];
    }
    __syncthreads();

    const int li = threadIdx.x;
    const int i  = i0 + li;
    if (i < NOUT) {
        // out(i) = sum_{rr=0..9} sum_{cc=0..9} x[i+rr][i+11+cc]
        // band offset o = (i+11+cc) - (i+rr) - 2 = (W-1) - rr + cc
        float acc = 0.0f;
        #pragma unroll
        for (int rr = 0; rr < W; ++rr) {
            const float* p = &band[(li + rr) * ROW_PAD + (W - 1 - rr)];
            #pragma unroll
            for (int cc = 0; cc < W; ++cc) acc += p[cc];
        }
        out[(size_t)b * NOUT + i] = acc * (1.0f / (W * W));
    }
}

extern "C" void kernel_launch(void* const* d_in, const int* in_sizes, int n_in,
                              void* d_out, int out_size, void* d_ws, size_t ws_size,
                              hipStream_t stream) {
    const float* x = (const float*)d_in[0];
    float* out = (float*)d_out;
    dim3 grid((NOUT + OUTS_PER_BLOCK - 1) / OUTS_PER_BLOCK, BPC);
    dim3 block(OUTS_PER_BLOCK);
    insulation_kernel<<<grid, block, 0, stream>>>(x, out);
}